// Round 2
// baseline (1506.910 us; speedup 1.0000x reference)
//
#include <hip/hip_runtime.h>
#include <hip/hip_bf16.h>
#include <stdint.h>

#define B_ 2
#define S_ 2048
#define D_ 4096
#define H_ 32
#define HD_ 128
#define HALF_ 64
#define AL_ 10
#define MROWS (B_*S_)   // 4096 rows of x / attn_out

typedef __hip_bfloat16 bf16;
typedef __attribute__((ext_vector_type(8))) __bf16 bf16x8;
typedef __attribute__((ext_vector_type(4))) float f32x4;
typedef __attribute__((ext_vector_type(4))) unsigned short us4;

// async global->LDS, 16B per lane. LDS dest = wave-uniform base + lane*16.
__device__ __forceinline__ void gld_lds16(const void* g, void* l) {
    __builtin_amdgcn_global_load_lds((const __attribute__((address_space(1))) void*)g,
                                     (__attribute__((address_space(3))) void*)l, 16, 0, 0);
}

// ---------------------------------------------------------------------------
// Input dtype detection. Interpret x's first 4096 uint16 as bf16: if inputs
// are fp32, the low half of each word is mantissa junk (~50% |v|>100, some
// NaN); if bf16, all values are sane N(0,1). flag=1 -> fp32 inputs.
// ---------------------------------------------------------------------------
__global__ void detect_dtype(const unsigned short* __restrict__ x, int* __restrict__ flag) {
    __shared__ int cnt;
    if (threadIdx.x == 0) cnt = 0;
    __syncthreads();
    int bad = 0;
#pragma unroll
    for (int i = 0; i < 16; i++) {
        unsigned int u = x[threadIdx.x * 16 + i];
        float v = __uint_as_float(u << 16);
        if (!(fabsf(v) < 1000.f)) bad++;   // also true for NaN/Inf
    }
    atomicAdd(&cnt, bad);
    __syncthreads();
    if (threadIdx.x == 0) flag[0] = (cnt > 64) ? 1 : 0;
}

// Convert input (fp32 or bf16 per flag) to canonical bf16. n % 4 == 0.
__global__ void convert_bf16(const void* __restrict__ in, bf16* __restrict__ out,
                             const int* __restrict__ flag, int n) {
    int i = (blockIdx.x * 256 + threadIdx.x) * 4;
    if (i >= n) return;
    if (flag[0]) {
        float4 f = *(const float4*)((const float*)in + i);
        out[i + 0] = __float2bfloat16(f.x);
        out[i + 1] = __float2bfloat16(f.y);
        out[i + 2] = __float2bfloat16(f.z);
        out[i + 3] = __float2bfloat16(f.w);
    } else {
        *(us4*)(out + i) = *(const us4*)((const unsigned short*)in + i);
    }
}

// ---------------------------------------------------------------------------
// GEMM: C = A (M x K, row-major) @ W^T (W is N x K, row-major), bf16 in, fp32 acc.
// MODE 0: RoPE + store to (B,H,S,HD)   (Q and K projections)
// MODE 1: store transposed to (B,H,HD,S)  (V projection)
// MODE 2: store to d_out as fp32 or bf16 per flag (output projection)
// Tile: 128x128 per block (256 thr = 4 waves, each wave 64x64 via 4x4 MFMA tiles),
// BK=64. LDS XOR-swizzled (chunk c of row r at c^(r&7)): global_load_lds stays
// linear, ds_read_b128 is <=2-way conflict (free).
// ---------------------------------------------------------------------------
template<int MODE>
__global__ __launch_bounds__(256) void gemm_bt(
    const bf16* __restrict__ A, const bf16* __restrict__ W,
    const bf16* __restrict__ cosb, const bf16* __restrict__ sinb,
    void* __restrict__ outv, const int* __restrict__ flag, int K)
{
    __shared__ __align__(16) bf16 sA[128*64];
    __shared__ __align__(16) bf16 sB[128*64];
    const int tid  = threadIdx.x;
    const int wave = tid >> 6, lane = tid & 63;
    const int quad = lane >> 4, col = lane & 15;
    const int m0 = blockIdx.y * 128, n0 = blockIdx.x * 128;
    const int wm = (wave >> 1) * 64, wn = (wave & 1) * 64;

    bool f32o = false;
    if (MODE == 2) f32o = (flag[0] != 0);

    f32x4 acc[4][4];
#pragma unroll
    for (int i = 0; i < 4; i++)
#pragma unroll
        for (int j = 0; j < 4; j++) acc[i][j] = {0.f, 0.f, 0.f, 0.f};

    for (int k0 = 0; k0 < K; k0 += 64) {
        __syncthreads();   // protect LDS from previous iteration's readers
#pragma unroll
        for (int i = 0; i < 4; i++) {
            int c   = i * 256 + tid;
            int row = c >> 3;                    // 8 chunks (64 elems) per row
            int cc  = (c & 7) ^ (row & 7);       // swizzled global chunk col
            gld_lds16(A + (size_t)(m0 + row) * K + k0 + cc * 8,
                      sA + (size_t)(i * 256 + wave * 64) * 8);
            gld_lds16(W + (size_t)(n0 + row) * K + k0 + cc * 8,
                      sB + (size_t)(i * 256 + wave * 64) * 8);
        }
        __syncthreads();   // drains vmcnt -> staging complete

#pragma unroll
        for (int kk = 0; kk < 64; kk += 32) {
            bf16x8 af[4], bfr[4];
#pragma unroll
            for (int mt = 0; mt < 4; mt++) {
                int r  = wm + mt * 16 + col;
                int ck = ((kk >> 3) + quad) ^ (r & 7);
                af[mt] = *(const bf16x8*)(sA + r * 64 + ck * 8);
            }
#pragma unroll
            for (int nt = 0; nt < 4; nt++) {
                int r  = wn + nt * 16 + col;
                int ck = ((kk >> 3) + quad) ^ (r & 7);
                bfr[nt] = *(const bf16x8*)(sB + r * 64 + ck * 8);
            }
#pragma unroll
            for (int mt = 0; mt < 4; mt++)
#pragma unroll
                for (int nt = 0; nt < 4; nt++)
                    acc[mt][nt] = __builtin_amdgcn_mfma_f32_16x16x32_bf16(
                        af[mt], bfr[nt], acc[mt][nt], 0, 0, 0);
        }
    }

    // Epilogue. C/D layout: col = lane&15, row = quad*4 + e (verified m89/m91).
#pragma unroll
    for (int mt = 0; mt < 4; mt++) {
#pragma unroll
        for (int nt = 0; nt < 4; nt++) {
            int n = n0 + wn + nt * 16 + col;
#pragma unroll
            for (int e = 0; e < 4; e++) {
                int m   = m0 + wm + mt * 16 + quad * 4 + e;
                float v = acc[mt][nt][e];
                if (MODE == 2) {
                    if (f32o) ((float*)outv)[(size_t)m * D_ + n] = v;
                    else      ((bf16*)outv)[(size_t)m * D_ + n] = __float2bfloat16(v);
                } else {
                    int b = m >> 11, s = m & (S_ - 1);
                    int h = n >> 7,  hd = n & (HD_ - 1);
                    bf16* out = (bf16*)outv;
                    if (MODE == 0) {
                        // RoPE: pairs (2i,2i+1) sit in adjacent lanes (col parity).
                        float other = __shfl_xor(v, 1);
                        float c  = __bfloat162float(cosb[s * HALF_ + (hd >> 1)]);
                        float sn = __bfloat162float(sinb[s * HALF_ + (hd >> 1)]);
                        float r  = (hd & 1) ? (v * c + other * sn)   // r1 = t0*s + t1*c
                                            : (v * c - other * sn);  // r0 = t0*c - t1*s
                        out[((size_t)(b * H_ + h) * S_ + s) * HD_ + hd] = __float2bfloat16(r);
                    } else { // MODE 1: V transposed -> (B,H,HD,S)
                        out[((size_t)(b * H_ + h) * HD_ + hd) * S_ + s] = __float2bfloat16(v);
                    }
                }
            }
        }
    }
}

// ---------------------------------------------------------------------------
// Flash attention, causal. Block = (b,h, 64-query tile), 256 thr = 4 waves,
// wave w owns query rows [w*16, w*16+16). K/V staged per 64-key tile.
// q,k: (B,H,S,HD)  v: (B,H,HD,S)  out: (B,S,H,HD)
// ---------------------------------------------------------------------------
__global__ __launch_bounds__(256) void attn_fwd(
    const bf16* __restrict__ q, const bf16* __restrict__ k,
    const bf16* __restrict__ vT, bf16* __restrict__ o)
{
    __shared__ __align__(16) bf16 sQ[64*128];
    __shared__ __align__(16) bf16 sK[64*128];
    __shared__ __align__(16) bf16 sV[128*64];
    __shared__ __align__(16) bf16 sP[64*64];

    const int tid  = threadIdx.x, wave = tid >> 6, lane = tid & 63;
    const int quad = lane >> 4, col = lane & 15;
    const int qt = blockIdx.x, bh = blockIdx.y;
    const int q0 = qt * 64;
    const bf16* qb = q  + (size_t)bh * S_ * HD_;
    const bf16* kb = k  + (size_t)bh * S_ * HD_;
    const bf16* vb = vT + (size_t)bh * HD_ * S_;

    // stage Q tile once (64 x 128)
#pragma unroll
    for (int i = 0; i < 4; i++) {
        int c = i * 256 + tid;
        int row = c >> 4;                       // 16 chunks per row
        int cc  = (c & 15) ^ (row & 7);
        gld_lds16(qb + (size_t)(q0 + row) * HD_ + cc * 8,
                  sQ + (size_t)(i * 256 + wave * 64) * 8);
    }

    float mst[4], lst[4];
#pragma unroll
    for (int e = 0; e < 4; e++) { mst[e] = -1e30f; lst[e] = 0.f; }
    f32x4 oacc[8];
#pragma unroll
    for (int i = 0; i < 8; i++) oacc[i] = {0.f, 0.f, 0.f, 0.f};

    const float scale = 0.08838834764831845f;  // 1/sqrt(128)

    for (int kt = 0; kt <= qt; kt++) {
        const int k0 = kt * 64;
        __syncthreads();   // all waves done reading sK/sV/sP from prev iter
#pragma unroll
        for (int i = 0; i < 4; i++) {
            int c = i * 256 + tid;
            int rowK = c >> 4, ccK = (c & 15) ^ (rowK & 7);
            gld_lds16(kb + (size_t)(k0 + rowK) * HD_ + ccK * 8,
                      sK + (size_t)(i * 256 + wave * 64) * 8);
            int rowV = c >> 3, ccV = (c & 7) ^ (rowV & 7);
            gld_lds16(vb + (size_t)rowV * S_ + k0 + ccV * 8,
                      sV + (size_t)(i * 256 + wave * 64) * 8);
        }
        __syncthreads();   // staging (and first-iter Q) complete

        // S = Q K^T : this wave's 16 rows x 64 keys
        f32x4 sc[4];
#pragma unroll
        for (int nt = 0; nt < 4; nt++) sc[nt] = {0.f, 0.f, 0.f, 0.f};
#pragma unroll
        for (int kk = 0; kk < 128; kk += 32) {
            int rq  = wave * 16 + col;
            int ckq = ((kk >> 3) + quad) ^ (rq & 7);
            bf16x8 aq = *(const bf16x8*)(sQ + rq * 128 + ckq * 8);
#pragma unroll
            for (int nt = 0; nt < 4; nt++) {
                int rk  = nt * 16 + col;
                int ckk = ((kk >> 3) + quad) ^ (rk & 7);
                bf16x8 bk = *(const bf16x8*)(sK + rk * 128 + ckk * 8);
                sc[nt] = __builtin_amdgcn_mfma_f32_16x16x32_bf16(aq, bk, sc[nt], 0, 0, 0);
            }
        }

        const bool diag = (kt == qt);
#pragma unroll
        for (int nt = 0; nt < 4; nt++)
#pragma unroll
            for (int e = 0; e < 4; e++) {
                float v = sc[nt][e] * scale;
                if (diag && (nt * 16 + col > wave * 16 + quad * 4 + e)) v = -1e30f;
                sc[nt][e] = v;
            }

        // online softmax update (each quad handles its own 4 rows)
        float alpha_[4];
#pragma unroll
        for (int e = 0; e < 4; e++) {
            float mx = fmaxf(fmaxf(sc[0][e], sc[1][e]), fmaxf(sc[2][e], sc[3][e]));
#pragma unroll
            for (int off = 1; off < 16; off <<= 1) mx = fmaxf(mx, __shfl_xor(mx, off));
            float mnew = fmaxf(mst[e], mx);
            float al   = __expf(mst[e] - mnew);
            float rs   = 0.f;
            int prow = wave * 16 + quad * 4 + e;
#pragma unroll
            for (int nt = 0; nt < 4; nt++) {
                float p = __expf(sc[nt][e] - mnew);
                rs += p;
                int pcol = nt * 16 + col;
                int pc   = (pcol >> 3) ^ (prow & 7);
                sP[prow * 64 + pc * 8 + (pcol & 7)] = __float2bfloat16(p);
            }
#pragma unroll
            for (int off = 1; off < 16; off <<= 1) rs += __shfl_xor(rs, off);
            lst[e] = lst[e] * al + rs;
            mst[e] = mnew;
            alpha_[e] = al;
        }
#pragma unroll
        for (int nt = 0; nt < 8; nt++)
#pragma unroll
            for (int e = 0; e < 4; e++) oacc[nt][e] *= alpha_[e];
        __syncthreads();   // sP visible before PV reads

        // O += P @ V  (P in A-layout via LDS round-trip; V^T rows = hd)
#pragma unroll
        for (int kk = 0; kk < 64; kk += 32) {
            int rp  = wave * 16 + col;
            int ckp = ((kk >> 3) + quad) ^ (rp & 7);
            bf16x8 pf = *(const bf16x8*)(sP + rp * 64 + ckp * 8);
#pragma unroll
            for (int nt = 0; nt < 8; nt++) {
                int rv  = nt * 16 + col;
                int ckv = ((kk >> 3) + quad) ^ (rv & 7);
                bf16x8 vf = *(const bf16x8*)(sV + rv * 64 + ckv * 8);
                oacc[nt] = __builtin_amdgcn_mfma_f32_16x16x32_bf16(pf, vf, oacc[nt], 0, 0, 0);
            }
        }
    }

    const int b = bh >> 5, h = bh & (H_ - 1);
#pragma unroll
    for (int e = 0; e < 4; e++) {
        int s = q0 + wave * 16 + quad * 4 + e;
        float inv = 1.f / lst[e];
#pragma unroll
        for (int nt = 0; nt < 8; nt++) {
            int hd = nt * 16 + col;
            o[((size_t)(b * S_ + s) * H_ + h) * HD_ + hd] =
                __float2bfloat16(oacc[nt][e] * inv);
        }
    }
}

// ---------------------------------------------------------------------------
// a_k / a_v = adapter (B,AL,D) @ w^T. One wave per (b, n); blockIdx.y picks w.
// Output fp32 (B,AL,D).
// ---------------------------------------------------------------------------
__global__ __launch_bounds__(256) void adapter_kv(
    const bf16* __restrict__ adp, const bf16* __restrict__ wk,
    const bf16* __restrict__ wv, float* __restrict__ ak, float* __restrict__ av)
{
    const int tid = threadIdx.x, wave = tid >> 6, lane = tid & 63;
    const int gid = blockIdx.x * 4 + wave;          // 0..8191
    const int n = gid & (D_ - 1), b = gid >> 12;
    const bf16* w    = blockIdx.y ? wv : wk;
    float*      outp = blockIdx.y ? av : ak;

    float acc[AL_];
#pragma unroll
    for (int j = 0; j < AL_; j++) acc[j] = 0.f;

    for (int t = 0; t < 8; t++) {
        int kb = t * 512 + lane * 8;
        bf16x8 w8 = *(const bf16x8*)(w + (size_t)n * D_ + kb);
        float wf[8];
#pragma unroll
        for (int i = 0; i < 8; i++) wf[i] = (float)w8[i];
#pragma unroll
        for (int j = 0; j < AL_; j++) {
            bf16x8 a8 = *(const bf16x8*)(adp + (size_t)(b * AL_ + j) * D_ + kb);
            float s = 0.f;
#pragma unroll
            for (int i = 0; i < 8; i++) s += (float)a8[i] * wf[i];
            acc[j] += s;
        }
    }
#pragma unroll
    for (int j = 0; j < AL_; j++) {
        float v = acc[j];
#pragma unroll
        for (int off = 1; off < 64; off <<= 1) v += __shfl_xor(v, off);
        if (lane == 0) outp[(size_t)(b * AL_ + j) * D_ + n] = v;
    }
}

// ---------------------------------------------------------------------------
// out += tanh(gate_h) * softmax(q . a_k^T * scale) @ a_v.  One wave per query.
// q: (B,H,S,HD) roped; out: (B,S,H,HD) bf16 (read-modify-write).
// ---------------------------------------------------------------------------
__global__ __launch_bounds__(256) void adapter_add(
    const bf16* __restrict__ q, const float* __restrict__ ak,
    const float* __restrict__ av, const bf16* __restrict__ gate,
    bf16* __restrict__ o)
{
    const int tid = threadIdx.x, wave = tid >> 6, lane = tid & 63;
    const int g = blockIdx.x * 4 + wave;            // (b*H+h)*S + s
    const int s = g & (S_ - 1);
    const int h = (g >> 11) & (H_ - 1);
    const int b = g >> 16;
    const int hd = lane * 2;

    const bf16* qp = q + ((size_t)(b * H_ + h) * S_ + s) * HD_ + hd;
    float q0f = __bfloat162float(qp[0]);
    float q1f = __bfloat162float(qp[1]);
    const float scale = 0.08838834764831845f;

    float sc[AL_];
#pragma unroll
    for (int j = 0; j < AL_; j++) {
        const float* akp = ak + (size_t)(b * AL_ + j) * D_ + h * HD_ + hd;
        float p = q0f * akp[0] + q1f * akp[1];
#pragma unroll
        for (int off = 1; off < 64; off <<= 1) p += __shfl_xor(p, off);
        sc[j] = p * scale;
    }
    float mx = sc[0];
#pragma unroll
    for (int j = 1; j < AL_; j++) mx = fmaxf(mx, sc[j]);
    float sum = 0.f;
#pragma unroll
    for (int j = 0; j < AL_; j++) { sc[j] = __expf(sc[j] - mx); sum += sc[j]; }
    float wgt = tanhf(__bfloat162float(gate[h])) / sum;

    float a0 = 0.f, a1 = 0.f;
#pragma unroll
    for (int j = 0; j < AL_; j++) {
        const float* avp = av + (size_t)(b * AL_ + j) * D_ + h * HD_ + hd;
        a0 += sc[j] * avp[0];
        a1 += sc[j] * avp[1];
    }
    bf16* op = o + ((size_t)(b * S_ + s) * H_ + h) * HD_ + hd;
    op[0] = __float2bfloat16(__bfloat162float(op[0]) + wgt * a0);
    op[1] = __float2bfloat16(__bfloat162float(op[1]) + wgt * a1);
}

// ---------------------------------------------------------------------------
extern "C" void kernel_launch(void* const* d_in, const int* in_sizes, int n_in,
                              void* d_out, int out_size, void* d_ws, size_t ws_size,
                              hipStream_t stream)
{
    const void* x_raw    = d_in[0];
    // d_in[1] = mask (causal, hard-coded)
    const void* cos_raw  = d_in[2];
    const void* sin_raw  = d_in[3];
    const void* wq_raw   = d_in[4];
    const void* wk_raw   = d_in[5];
    const void* wv_raw   = d_in[6];
    const void* wo_raw   = d_in[7];
    const void* gate_raw = d_in[8];
    const void* adp_raw  = d_in[9];
    // d_in[10] = start_pos (0, unused by reference)

    const size_t NE = (size_t)B_ * S_ * D_;     // 16777216
    const int    CS = S_ * HALF_;               // cos/sin elements = 131072
    const int    AD = B_ * AL_ * D_;            // adapter elements = 81920

    // ws layout (bf16 unless noted). ab aliases xc (x dead after V-projection).
    bf16* xc   = (bf16*)d_ws;            // NE   (later reused as ab)
    bf16* wqc  = xc  + NE;               // NE
    bf16* wkc  = wqc + NE;               // NE
    bf16* wvc  = wkc + NE;               // NE
    bf16* woc  = wvc + NE;               // NE
    bf16* qb   = woc + NE;               // NE (roped Q,  B,H,S,HD)
    bf16* kb   = qb  + NE;               // NE (roped K,  B,H,S,HD)
    bf16* vb   = kb  + NE;               // NE (V^T,      B,H,HD,S)
    bf16* cosc = vb  + NE;               // CS
    bf16* sinc = cosc + CS;              // CS
    bf16* adpc = sinc + CS;              // AD
    bf16* gatec= adpc + AD;              // 32
    float* akb = (float*)(gatec + 32);   // AD fp32
    float* avb = akb + AD;               // AD fp32
    int*  flag = (int*)(avb + AD);       // 1
    bf16* ab   = xc;                     // attention out (B,S,H,HD), aliases xc

    dim3 blk(256);
    detect_dtype<<<1, 256, 0, stream>>>((const unsigned short*)x_raw, flag);

    convert_bf16<<<dim3((int)(NE/4 + 255) / 256), blk, 0, stream>>>(x_raw,  xc,  flag, (int)NE);
    convert_bf16<<<dim3((int)(NE/4 + 255) / 256), blk, 0, stream>>>(wq_raw, wqc, flag, (int)NE);
    convert_bf16<<<dim3((int)(NE/4 + 255) / 256), blk, 0, stream>>>(wk_raw, wkc, flag, (int)NE);
    convert_bf16<<<dim3((int)(NE/4 + 255) / 256), blk, 0, stream>>>(wv_raw, wvc, flag, (int)NE);
    convert_bf16<<<dim3((int)(NE/4 + 255) / 256), blk, 0, stream>>>(wo_raw, woc, flag, (int)NE);
    convert_bf16<<<dim3((CS/4 + 255) / 256), blk, 0, stream>>>(cos_raw,  cosc, flag, CS);
    convert_bf16<<<dim3((CS/4 + 255) / 256), blk, 0, stream>>>(sin_raw,  sinc, flag, CS);
    convert_bf16<<<dim3((AD/4 + 255) / 256), blk, 0, stream>>>(adp_raw,  adpc, flag, AD);
    convert_bf16<<<dim3(1), blk, 0, stream>>>(gate_raw, gatec, flag, 32);

    dim3 gg(D_ / 128, MROWS / 128);
    gemm_bt<0><<<gg, blk, 0, stream>>>(xc, wqc, cosc, sinc, qb, flag, D_);
    gemm_bt<0><<<gg, blk, 0, stream>>>(xc, wkc, cosc, sinc, kb, flag, D_);
    gemm_bt<1><<<gg, blk, 0, stream>>>(xc, wvc, cosc, sinc, vb, flag, D_);
    adapter_kv<<<dim3(2048, 2), blk, 0, stream>>>(adpc, wkc, wvc, akb, avb);
    attn_fwd<<<dim3(S_ / 64, B_ * H_), blk, 0, stream>>>(qb, kb, vb, ab);
    adapter_add<<<dim3(B_ * H_ * S_ / 4), blk, 0, stream>>>(qb, akb, avb, gatec, ab);
    gemm_bt<2><<<gg, blk, 0, stream>>>(ab, woc, cosc, sinc, d_out, flag, D_);
}

// Round 3
// 1500.698 us; speedup vs baseline: 1.0041x; 1.0041x over previous
//
#include <hip/hip_runtime.h>
#include <hip/hip_bf16.h>
#include <stdint.h>

#define B_ 2
#define S_ 2048
#define D_ 4096
#define H_ 32
#define HD_ 128
#define HALF_ 64
#define AL_ 10
#define MROWS (B_*S_)   // 4096 rows of x / attn_out

typedef __hip_bfloat16 bf16;
typedef __attribute__((ext_vector_type(8))) __bf16 bf16x8;
typedef __attribute__((ext_vector_type(4))) float f32x4;
typedef __attribute__((ext_vector_type(4))) unsigned short us4;

// async global->LDS, 16B per lane. LDS dest = wave-uniform base + lane*16.
__device__ __forceinline__ void gld_lds16(const void* g, void* l) {
    __builtin_amdgcn_global_load_lds((const __attribute__((address_space(1))) void*)g,
                                     (__attribute__((address_space(3))) void*)l, 16, 0, 0);
}

// ---------------------------------------------------------------------------
// Input dtype detection. flag=1 -> fp32 inputs (low half of fp32 read as bf16
// is mantissa junk), flag=0 -> already bf16.
// ---------------------------------------------------------------------------
__global__ void detect_dtype(const unsigned short* __restrict__ x, int* __restrict__ flag) {
    __shared__ int cnt;
    if (threadIdx.x == 0) cnt = 0;
    __syncthreads();
    int bad = 0;
#pragma unroll
    for (int i = 0; i < 16; i++) {
        unsigned int u = x[threadIdx.x * 16 + i];
        float v = __uint_as_float(u << 16);
        if (!(fabsf(v) < 1000.f)) bad++;   // also true for NaN/Inf
    }
    atomicAdd(&cnt, bad);
    __syncthreads();
    if (threadIdx.x == 0) flag[0] = (cnt > 64) ? 1 : 0;
}

// Convert input (fp32 or bf16 per flag) to canonical bf16. n % 4 == 0.
__global__ void convert_bf16(const void* __restrict__ in, bf16* __restrict__ out,
                             const int* __restrict__ flag, int n) {
    int i = (blockIdx.x * 256 + threadIdx.x) * 4;
    if (i >= n) return;
    if (flag[0]) {
        float4 f = *(const float4*)((const float*)in + i);
        out[i + 0] = __float2bfloat16(f.x);
        out[i + 1] = __float2bfloat16(f.y);
        out[i + 2] = __float2bfloat16(f.z);
        out[i + 3] = __float2bfloat16(f.w);
    } else {
        *(us4*)(out + i) = *(const us4*)((const unsigned short*)in + i);
    }
}

// ---------------------------------------------------------------------------
// GEMM: C = A (M x K, row-major) @ W^T (W is N x K, row-major), bf16 in, fp32 acc.
// MODE 0: RoPE + store to (B,H,S,HD)   (Q and K projections)
// MODE 1: store transposed to (B,H,HD,S)  (V projection)
// MODE 2: store to d_out as fp32 or bf16 per flag (output projection)
// ---------------------------------------------------------------------------
template<int MODE>
__global__ __launch_bounds__(256) void gemm_bt(
    const bf16* __restrict__ A, const bf16* __restrict__ W,
    const bf16* __restrict__ cosb, const bf16* __restrict__ sinb,
    void* __restrict__ outv, const int* __restrict__ flag, int K)
{
    __shared__ __align__(16) bf16 sA[128*64];
    __shared__ __align__(16) bf16 sB[128*64];
    const int tid  = threadIdx.x;
    const int wave = tid >> 6, lane = tid & 63;
    const int quad = lane >> 4, col = lane & 15;
    const int m0 = blockIdx.y * 128, n0 = blockIdx.x * 128;
    const int wm = (wave >> 1) * 64, wn = (wave & 1) * 64;

    bool f32o = false;
    if (MODE == 2) f32o = (flag[0] != 0);

    f32x4 acc[4][4];
#pragma unroll
    for (int i = 0; i < 4; i++)
#pragma unroll
        for (int j = 0; j < 4; j++) acc[i][j] = {0.f, 0.f, 0.f, 0.f};

    for (int k0 = 0; k0 < K; k0 += 64) {
        __syncthreads();
#pragma unroll
        for (int i = 0; i < 4; i++) {
            int c   = i * 256 + tid;
            int row = c >> 3;
            int cc  = (c & 7) ^ (row & 7);
            gld_lds16(A + (size_t)(m0 + row) * K + k0 + cc * 8,
                      sA + (size_t)(i * 256 + wave * 64) * 8);
            gld_lds16(W + (size_t)(n0 + row) * K + k0 + cc * 8,
                      sB + (size_t)(i * 256 + wave * 64) * 8);
        }
        __syncthreads();

#pragma unroll
        for (int kk = 0; kk < 64; kk += 32) {
            bf16x8 af[4], bfr[4];
#pragma unroll
            for (int mt = 0; mt < 4; mt++) {
                int r  = wm + mt * 16 + col;
                int ck = ((kk >> 3) + quad) ^ (r & 7);
                af[mt] = *(const bf16x8*)(sA + r * 64 + ck * 8);
            }
#pragma unroll
            for (int nt = 0; nt < 4; nt++) {
                int r  = wn + nt * 16 + col;
                int ck = ((kk >> 3) + quad) ^ (r & 7);
                bfr[nt] = *(const bf16x8*)(sB + r * 64 + ck * 8);
            }
#pragma unroll
            for (int mt = 0; mt < 4; mt++)
#pragma unroll
                for (int nt = 0; nt < 4; nt++)
                    acc[mt][nt] = __builtin_amdgcn_mfma_f32_16x16x32_bf16(
                        af[mt], bfr[nt], acc[mt][nt], 0, 0, 0);
        }
    }

    // C/D layout: col = lane&15, row = quad*4 + e (verified m89/m91).
#pragma unroll
    for (int mt = 0; mt < 4; mt++) {
#pragma unroll
        for (int nt = 0; nt < 4; nt++) {
            int n = n0 + wn + nt * 16 + col;
#pragma unroll
            for (int e = 0; e < 4; e++) {
                int m   = m0 + wm + mt * 16 + quad * 4 + e;
                float v = acc[mt][nt][e];
                if (MODE == 2) {
                    if (f32o) ((float*)outv)[(size_t)m * D_ + n] = v;
                    else      ((bf16*)outv)[(size_t)m * D_ + n] = __float2bfloat16(v);
                } else {
                    int b = m >> 11, s = m & (S_ - 1);
                    int h = n >> 7,  hd = n & (HD_ - 1);
                    bf16* out = (bf16*)outv;
                    if (MODE == 0) {
                        float other = __shfl_xor(v, 1);
                        float c  = __bfloat162float(cosb[s * HALF_ + (hd >> 1)]);
                        float sn = __bfloat162float(sinb[s * HALF_ + (hd >> 1)]);
                        float r  = (hd & 1) ? (v * c + other * sn)
                                            : (v * c - other * sn);
                        out[((size_t)(b * H_ + h) * S_ + s) * HD_ + hd] = __float2bfloat16(r);
                    } else { // MODE 1: V transposed -> (B,H,HD,S)
                        out[((size_t)(b * H_ + h) * HD_ + hd) * S_ + s] = __float2bfloat16(v);
                    }
                }
            }
        }
    }
}

// ---------------------------------------------------------------------------
// Flash attention, causal. Block = (b,h, 128-query tile), 256 thr = 4 waves.
// Wave w owns query rows [w*32, w*32+32) as two 16-row MFMA subtiles (rq=0,1).
// Q A-fragments held in registers (staged once via reused LDS). Per 64-key
// tile: stage K (64x128) + V^T (128x64), QK -> online softmax -> sP (wave-
// private rows, NO barrier before PV) -> PV. 2 barriers/iter. LDS 48KB.
// q,k: (B,H,S,HD)  v: (B,H,HD,S)  out: (B,S,H,HD)
// ---------------------------------------------------------------------------
__global__ __launch_bounds__(256, 2) void attn_fwd(
    const bf16* __restrict__ q, const bf16* __restrict__ k,
    const bf16* __restrict__ vT, bf16* __restrict__ o)
{
    __shared__ __align__(16) bf16 smem[24576];   // 48 KB
    bf16* sK = smem;            // 64 rows x 128  (16 KB)
    bf16* sV = smem + 8192;     // 128 rows(hd) x 64 keys (16 KB)
    bf16* sP = smem + 16384;    // 128 rows x 64  (16 KB)

    const int tid  = threadIdx.x, wave = tid >> 6, lane = tid & 63;
    const int quad = lane >> 4, col = lane & 15;
    const int qt = (gridDim.x - 1) - blockIdx.x;   // reverse: heavy blocks first
    const int bh = blockIdx.y;
    const int q0 = qt * 128;
    const bf16* qb = q  + (size_t)bh * S_ * HD_;
    const bf16* kb = k  + (size_t)bh * S_ * HD_;
    const bf16* vb = vT + (size_t)bh * HD_ * S_;

    // ---- stage Q tile (128x128 = 32KB) into sK|sV region, then to registers
#pragma unroll
    for (int i = 0; i < 8; i++) {
        int c = i * 256 + tid;
        int row = c >> 4;                       // 16 chunks per row
        int cc  = (c & 15) ^ (row & 7);
        gld_lds16(qb + (size_t)(q0 + row) * HD_ + cc * 8,
                  smem + (size_t)(i * 256 + wave * 64) * 8);
    }
    __syncthreads();

    bf16x8 qf[2][4];
#pragma unroll
    for (int rq = 0; rq < 2; rq++) {
        int row = wave * 32 + rq * 16 + col;
#pragma unroll
        for (int kkI = 0; kkI < 4; kkI++) {
            int ck = (kkI * 4 + quad) ^ (row & 7);
            qf[rq][kkI] = *(const bf16x8*)(smem + row * 128 + ck * 8);
        }
    }

    float mst[2][4], lst[2][4];
#pragma unroll
    for (int rq = 0; rq < 2; rq++)
#pragma unroll
        for (int e = 0; e < 4; e++) { mst[rq][e] = -1e30f; lst[rq][e] = 0.f; }
    f32x4 oacc[2][8];
#pragma unroll
    for (int rq = 0; rq < 2; rq++)
#pragma unroll
        for (int i = 0; i < 8; i++) oacc[rq][i] = {0.f, 0.f, 0.f, 0.f};

    const float scale = 0.08838834764831845f;  // 1/sqrt(128)
    const int ktEnd = 2 * qt + 2;

    for (int kt = 0; kt < ktEnd; kt++) {
        const int k0 = kt * 64;
        __syncthreads();   // waves done reading sK/sV (or Q frags loaded)
#pragma unroll
        for (int i = 0; i < 4; i++) {
            int c = i * 256 + tid;
            int rowK = c >> 4, ccK = (c & 15) ^ (rowK & 7);
            gld_lds16(kb + (size_t)(k0 + rowK) * HD_ + ccK * 8,
                      sK + (size_t)(i * 256 + wave * 64) * 8);
            int rowV = c >> 3, ccV = (c & 7) ^ (rowV & 7);
            gld_lds16(vb + (size_t)rowV * S_ + k0 + ccV * 8,
                      sV + (size_t)(i * 256 + wave * 64) * 8);
        }
        __syncthreads();   // staging complete

        // ---- S = Q K^T : 32 rows x 64 keys per wave
        f32x4 sc[2][4];
#pragma unroll
        for (int rq = 0; rq < 2; rq++)
#pragma unroll
            for (int nt = 0; nt < 4; nt++) sc[rq][nt] = {0.f, 0.f, 0.f, 0.f};
#pragma unroll
        for (int kkI = 0; kkI < 4; kkI++) {
#pragma unroll
            for (int nt = 0; nt < 4; nt++) {
                int rk  = nt * 16 + col;
                int ckk = (kkI * 4 + quad) ^ (rk & 7);
                bf16x8 bk = *(const bf16x8*)(sK + rk * 128 + ckk * 8);
                sc[0][nt] = __builtin_amdgcn_mfma_f32_16x16x32_bf16(qf[0][kkI], bk, sc[0][nt], 0, 0, 0);
                sc[1][nt] = __builtin_amdgcn_mfma_f32_16x16x32_bf16(qf[1][kkI], bk, sc[1][nt], 0, 0, 0);
            }
        }

        const bool diag = (kt >= 2 * qt);   // only last two tiles touch the diagonal
#pragma unroll
        for (int rq = 0; rq < 2; rq++)
#pragma unroll
            for (int nt = 0; nt < 4; nt++)
#pragma unroll
                for (int e = 0; e < 4; e++) {
                    float v = sc[rq][nt][e] * scale;
                    if (diag && (k0 + nt * 16 + col > q0 + wave * 32 + rq * 16 + quad * 4 + e))
                        v = -1e30f;
                    sc[rq][nt][e] = v;
                }

        // ---- online softmax (per-row state replicated across the quad's 16 lanes)
        float alpha_[2][4];
#pragma unroll
        for (int rq = 0; rq < 2; rq++)
#pragma unroll
            for (int e = 0; e < 4; e++) {
                float mx = fmaxf(fmaxf(sc[rq][0][e], sc[rq][1][e]),
                                 fmaxf(sc[rq][2][e], sc[rq][3][e]));
#pragma unroll
                for (int off = 1; off < 16; off <<= 1) mx = fmaxf(mx, __shfl_xor(mx, off));
                float mnew = fmaxf(mst[rq][e], mx);
                float al   = __expf(mst[rq][e] - mnew);
                float rs   = 0.f;
                int prow = wave * 32 + rq * 16 + quad * 4 + e;
#pragma unroll
                for (int nt = 0; nt < 4; nt++) {
                    float p = __expf(sc[rq][nt][e] - mnew);
                    rs += p;
                    int pcol = nt * 16 + col;
                    int pc   = (pcol >> 3) ^ (prow & 7);
                    sP[prow * 64 + pc * 8 + (pcol & 7)] = __float2bfloat16(p);
                }
#pragma unroll
                for (int off = 1; off < 16; off <<= 1) rs += __shfl_xor(rs, off);
                lst[rq][e] = lst[rq][e] * al + rs;
                mst[rq][e] = mnew;
                alpha_[rq][e] = al;
            }
#pragma unroll
        for (int rq = 0; rq < 2; rq++)
#pragma unroll
            for (int nt = 0; nt < 8; nt++)
#pragma unroll
                for (int e = 0; e < 4; e++) oacc[rq][nt][e] *= alpha_[rq][e];

        // ---- O += P @ V. sP rows [wave*32, wave*32+32) are wave-private:
        // no __syncthreads needed, lgkmcnt ordering suffices.
#pragma unroll
        for (int kkI = 0; kkI < 2; kkI++) {
            bf16x8 pf[2];
#pragma unroll
            for (int rq = 0; rq < 2; rq++) {
                int rp  = wave * 32 + rq * 16 + col;
                int ckp = (kkI * 4 + quad) ^ (rp & 7);
                pf[rq] = *(const bf16x8*)(sP + rp * 64 + ckp * 8);
            }
#pragma unroll
            for (int nt = 0; nt < 8; nt++) {
                int rv  = nt * 16 + col;
                int ckv = (kkI * 4 + quad) ^ (rv & 7);
                bf16x8 vf = *(const bf16x8*)(sV + rv * 64 + ckv * 8);
                oacc[0][nt] = __builtin_amdgcn_mfma_f32_16x16x32_bf16(pf[0], vf, oacc[0][nt], 0, 0, 0);
                oacc[1][nt] = __builtin_amdgcn_mfma_f32_16x16x32_bf16(pf[1], vf, oacc[1][nt], 0, 0, 0);
            }
        }
    }

    const int b = bh >> 5, h = bh & (H_ - 1);
#pragma unroll
    for (int rq = 0; rq < 2; rq++)
#pragma unroll
        for (int e = 0; e < 4; e++) {
            int s = q0 + wave * 32 + rq * 16 + quad * 4 + e;
            float inv = 1.f / lst[rq][e];
#pragma unroll
            for (int nt = 0; nt < 8; nt++) {
                int hd = nt * 16 + col;
                o[((size_t)(b * S_ + s) * H_ + h) * HD_ + hd] =
                    __float2bfloat16(oacc[rq][nt][e] * inv);
            }
        }
}

// ---------------------------------------------------------------------------
// a_k / a_v = adapter (B,AL,D) @ w^T. One wave per (b, n); blockIdx.y picks w.
// ---------------------------------------------------------------------------
__global__ __launch_bounds__(256) void adapter_kv(
    const bf16* __restrict__ adp, const bf16* __restrict__ wk,
    const bf16* __restrict__ wv, float* __restrict__ ak, float* __restrict__ av)
{
    const int tid = threadIdx.x, wave = tid >> 6, lane = tid & 63;
    const int gid = blockIdx.x * 4 + wave;
    const int n = gid & (D_ - 1), b = gid >> 12;
    const bf16* w    = blockIdx.y ? wv : wk;
    float*      outp = blockIdx.y ? av : ak;

    float acc[AL_];
#pragma unroll
    for (int j = 0; j < AL_; j++) acc[j] = 0.f;

    for (int t = 0; t < 8; t++) {
        int kb = t * 512 + lane * 8;
        bf16x8 w8 = *(const bf16x8*)(w + (size_t)n * D_ + kb);
        float wf[8];
#pragma unroll
        for (int i = 0; i < 8; i++) wf[i] = (float)w8[i];
#pragma unroll
        for (int j = 0; j < AL_; j++) {
            bf16x8 a8 = *(const bf16x8*)(adp + (size_t)(b * AL_ + j) * D_ + kb);
            float s = 0.f;
#pragma unroll
            for (int i = 0; i < 8; i++) s += (float)a8[i] * wf[i];
            acc[j] += s;
        }
    }
#pragma unroll
    for (int j = 0; j < AL_; j++) {
        float v = acc[j];
#pragma unroll
        for (int off = 1; off < 64; off <<= 1) v += __shfl_xor(v, off);
        if (lane == 0) outp[(size_t)(b * AL_ + j) * D_ + n] = v;
    }
}

// ---------------------------------------------------------------------------
// out += tanh(gate_h) * softmax(q . a_k^T * scale) @ a_v.  One wave per query.
// ---------------------------------------------------------------------------
__global__ __launch_bounds__(256) void adapter_add(
    const bf16* __restrict__ q, const float* __restrict__ ak,
    const float* __restrict__ av, const bf16* __restrict__ gate,
    bf16* __restrict__ o)
{
    const int tid = threadIdx.x, wave = tid >> 6, lane = tid & 63;
    const int g = blockIdx.x * 4 + wave;
    const int s = g & (S_ - 1);
    const int h = (g >> 11) & (H_ - 1);
    const int b = g >> 16;
    const int hd = lane * 2;

    const bf16* qp = q + ((size_t)(b * H_ + h) * S_ + s) * HD_ + hd;
    float q0f = __bfloat162float(qp[0]);
    float q1f = __bfloat162float(qp[1]);
    const float scale = 0.08838834764831845f;

    float sc[AL_];
#pragma unroll
    for (int j = 0; j < AL_; j++) {
        const float* akp = ak + (size_t)(b * AL_ + j) * D_ + h * HD_ + hd;
        float p = q0f * akp[0] + q1f * akp[1];
#pragma unroll
        for (int off = 1; off < 64; off <<= 1) p += __shfl_xor(p, off);
        sc[j] = p * scale;
    }
    float mx = sc[0];
#pragma unroll
    for (int j = 1; j < AL_; j++) mx = fmaxf(mx, sc[j]);
    float sum = 0.f;
#pragma unroll
    for (int j = 0; j < AL_; j++) { sc[j] = __expf(sc[j] - mx); sum += sc[j]; }
    float wgt = tanhf(__bfloat162float(gate[h])) / sum;

    float a0 = 0.f, a1 = 0.f;
#pragma unroll
    for (int j = 0; j < AL_; j++) {
        const float* avp = av + (size_t)(b * AL_ + j) * D_ + h * HD_ + hd;
        a0 += sc[j] * avp[0];
        a1 += sc[j] * avp[1];
    }
    bf16* op = o + ((size_t)(b * S_ + s) * H_ + h) * HD_ + hd;
    op[0] = __float2bfloat16(__bfloat162float(op[0]) + wgt * a0);
    op[1] = __float2bfloat16(__bfloat162float(op[1]) + wgt * a1);
}

// ---------------------------------------------------------------------------
extern "C" void kernel_launch(void* const* d_in, const int* in_sizes, int n_in,
                              void* d_out, int out_size, void* d_ws, size_t ws_size,
                              hipStream_t stream)
{
    const void* x_raw    = d_in[0];
    const void* cos_raw  = d_in[2];
    const void* sin_raw  = d_in[3];
    const void* wq_raw   = d_in[4];
    const void* wk_raw   = d_in[5];
    const void* wv_raw   = d_in[6];
    const void* wo_raw   = d_in[7];
    const void* gate_raw = d_in[8];
    const void* adp_raw  = d_in[9];

    const size_t NE = (size_t)B_ * S_ * D_;     // 16777216
    const int    CS = S_ * HALF_;               // 131072
    const int    AD = B_ * AL_ * D_;            // 81920

    bf16* xc   = (bf16*)d_ws;            // NE   (later reused as ab)
    bf16* wqc  = xc  + NE;               // NE
    bf16* wkc  = wqc + NE;               // NE
    bf16* wvc  = wkc + NE;               // NE
    bf16* woc  = wvc + NE;               // NE
    bf16* qb   = woc + NE;               // NE (roped Q,  B,H,S,HD)
    bf16* kb   = qb  + NE;               // NE (roped K,  B,H,S,HD)
    bf16* vb   = kb  + NE;               // NE (V^T,      B,H,HD,S)
    bf16* cosc = vb  + NE;               // CS
    bf16* sinc = cosc + CS;              // CS
    bf16* adpc = sinc + CS;              // AD
    bf16* gatec= adpc + AD;              // 32
    float* akb = (float*)(gatec + 32);   // AD fp32
    float* avb = akb + AD;               // AD fp32
    int*  flag = (int*)(avb + AD);       // 1
    bf16* ab   = xc;                     // attention out (B,S,H,HD), aliases xc

    dim3 blk(256);
    detect_dtype<<<1, 256, 0, stream>>>((const unsigned short*)x_raw, flag);

    convert_bf16<<<dim3((int)(NE/4 + 255) / 256), blk, 0, stream>>>(x_raw,  xc,  flag, (int)NE);
    convert_bf16<<<dim3((int)(NE/4 + 255) / 256), blk, 0, stream>>>(wq_raw, wqc, flag, (int)NE);
    convert_bf16<<<dim3((int)(NE/4 + 255) / 256), blk, 0, stream>>>(wk_raw, wkc, flag, (int)NE);
    convert_bf16<<<dim3((int)(NE/4 + 255) / 256), blk, 0, stream>>>(wv_raw, wvc, flag, (int)NE);
    convert_bf16<<<dim3((int)(NE/4 + 255) / 256), blk, 0, stream>>>(wo_raw, woc, flag, (int)NE);
    convert_bf16<<<dim3((CS/4 + 255) / 256), blk, 0, stream>>>(cos_raw,  cosc, flag, CS);
    convert_bf16<<<dim3((CS/4 + 255) / 256), blk, 0, stream>>>(sin_raw,  sinc, flag, CS);
    convert_bf16<<<dim3((AD/4 + 255) / 256), blk, 0, stream>>>(adp_raw,  adpc, flag, AD);
    convert_bf16<<<dim3(1), blk, 0, stream>>>(gate_raw, gatec, flag, 32);

    dim3 gg(D_ / 128, MROWS / 128);
    gemm_bt<0><<<gg, blk, 0, stream>>>(xc, wqc, cosc, sinc, qb, flag, D_);
    gemm_bt<0><<<gg, blk, 0, stream>>>(xc, wkc, cosc, sinc, kb, flag, D_);
    gemm_bt<1><<<gg, blk, 0, stream>>>(xc, wvc, cosc, sinc, vb, flag, D_);
    adapter_kv<<<dim3(2048, 2), blk, 0, stream>>>(adpc, wkc, wvc, akb, avb);
    attn_fwd<<<dim3(S_ / 128, B_ * H_), blk, 0, stream>>>(qb, kb, vb, ab);
    adapter_add<<<dim3(B_ * H_ * S_ / 4), blk, 0, stream>>>(qb, akb, avb, gatec, ab);
    gemm_bt<2><<<gg, blk, 0, stream>>>(ab, woc, cosc, sinc, d_out, flag, D_);
}